// Round 3
// baseline (207.019 us; speedup 1.0000x reference)
//
#include <hip/hip_runtime.h>
#include <hip/hip_bf16.h>
#include <stdint.h>

typedef __attribute__((ext_vector_type(8))) short bf16x8;   // 8 bf16 = 4 VGPRs
typedef __attribute__((ext_vector_type(4))) float f32x4;
typedef __attribute__((ext_vector_type(4))) unsigned u32x4;

#define MFMA16(A,B,C) __builtin_amdgcn_mfma_f32_16x16x32_bf16(A,B,C,0,0,0)

// Fragment layouts (verified m89/m91 ladder):
//  A-frag: lane l holds A[m=l&15][k=(l>>4)*8+j], j=0..7   (k-contiguous)
//  B-frag: lane l holds B^T[n=l&15][k=(l>>4)*8+j]         (k-contiguous)
//  C/D:    lane l reg r holds D[m=(l>>4)*4+r][n=l&15]

// async 16B global->LDS
__device__ inline void gld_lds16(const __hip_bfloat16* g, __hip_bfloat16* l) {
  __builtin_amdgcn_global_load_lds(
      (const __attribute__((address_space(1))) void*)g,
      (__attribute__((address_space(3))) void*)l, 16, 0, 0);
}

// pack two f32 -> one b32 holding (bf16(a) | bf16(b)<<16)
__device__ inline unsigned pkbf(float a, float b) {
  __hip_bfloat162 t = __float22bfloat162_rn(float2{a, b});
  return *(unsigned*)&t;
}

// Quad redistribution for the S^T->A-frag transform.
// In:  a = pk[c2=0][u], b = pk[c2=1][u]  (per-lane packed score pairs)
// Out: a' rows(16-lane) = [a.r0, a.r2, b.r0, b.r2]  (A-frag reg for j=2u,2u+1)
//      b' rows          = [a.r1, a.r3, b.r1, b.r3]  (A-frag reg for j=4+2u,..)
__device__ inline void quad_mix(unsigned &a, unsigned &b) {
#if __has_builtin(__builtin_amdgcn_permlane32_swap) && __has_builtin(__builtin_amdgcn_permlane16_swap)
  auto r1 = __builtin_amdgcn_permlane32_swap(a, b, false, false);
  auto r2 = __builtin_amdgcn_permlane16_swap(r1[0], r1[1], false, false);
  a = r2[0];
  b = r2[1];
#else
  int lane = (int)(threadIdx.x & 63);
  int g = lane >> 4;
  int lm = lane & 15;
  int slo = (((g << 1) & 3) << 4) | lm;
  int shi = ((((g << 1) | 1) & 3) << 4) | lm;
  unsigned t0 = (unsigned)__shfl((int)a, slo, 64);
  unsigned t1 = (unsigned)__shfl((int)b, slo, 64);
  unsigned t2 = (unsigned)__shfl((int)a, shi, 64);
  unsigned t3 = (unsigned)__shfl((int)b, shi, 64);
  bool hi = g >= 2;
  unsigned na = hi ? t1 : t0;
  unsigned nb = hi ? t3 : t2;
  a = na;
  b = nb;
#endif
}

// ---------------------------------------------------------------------------
// f32 -> bf16 bulk convert (one-time; x / W_attn / W_proj)
// ---------------------------------------------------------------------------
__global__ __launch_bounds__(256)
void cvt_bf16(const float* __restrict__ s0, __hip_bfloat16* __restrict__ d0, int n0,
              const float* __restrict__ s1, __hip_bfloat16* __restrict__ d1, int n1,
              const float* __restrict__ s2, __hip_bfloat16* __restrict__ d2, int n2)
{
  const float* s; __hip_bfloat16* d; int n;
  if      (blockIdx.y == 0) { s = s0; d = d0; n = n0; }
  else if (blockIdx.y == 1) { s = s1; d = d1; n = n1; }
  else                      { s = s2; d = d2; n = n2; }
  int idx = (blockIdx.x * 256 + threadIdx.x) * 8;
  if (idx >= n) return;
  float4 u0 = *(const float4*)(s + idx);
  float4 u1 = *(const float4*)(s + idx + 4);
  __hip_bfloat16 t[8];
  t[0] = __float2bfloat16(u0.x); t[1] = __float2bfloat16(u0.y);
  t[2] = __float2bfloat16(u0.z); t[3] = __float2bfloat16(u0.w);
  t[4] = __float2bfloat16(u1.x); t[5] = __float2bfloat16(u1.y);
  t[6] = __float2bfloat16(u1.z); t[7] = __float2bfloat16(u1.w);
  *(int4*)(d + idx) = *(const int4*)t;
}

// ---------------------------------------------------------------------------
// GEMM (bf16): C[m][n] = sum_k A[m*K+k]*B[n*K+k] (+bias[n])
// BMxBN tile, BK=32, global_load_lds staging, stride-32 LDS.
// vtg mode (QKV projection): V third (bn>=2048) stored transposed into vtg;
// Q third (bn<1024) pre-scaled by (1/8)*log2(e) so softmax uses bare exp2.
// ---------------------------------------------------------------------------
template<int BM, int BN, typename TC>
__global__ __launch_bounds__(256)
void gemm_bt(const __hip_bfloat16* __restrict__ A,
             const __hip_bfloat16* __restrict__ B,
             TC* __restrict__ C,
             const float* __restrict__ bias,
             __hip_bfloat16* __restrict__ vtg,
             int M, int N, int K)
{
  constexpr int MI = BM / 32;
  constexpr int NJ = BN / 32;
  constexpr int NP = (BM + BN) / 64;

  __shared__ __align__(16) __hip_bfloat16 As[BM * 32];
  __shared__ __align__(16) __hip_bfloat16 Bs[BN * 32];

  const int tid  = threadIdx.x;
  const int lane = tid & 63;
  const int w    = tid >> 6;
  const int lm   = lane & 15;
  const int g    = lane >> 4;

  const int bm = blockIdx.y * BM;
  const int bn = blockIdx.x * BN;
  const int rm = (w >> 1) * (BM / 2);
  const int cn = (w & 1) * (BN / 2);

  const f32x4 fzero = {0.0f, 0.0f, 0.0f, 0.0f};
  f32x4 acc[MI][NJ];
  for (int i = 0; i < MI; i++)
    for (int j = 0; j < NJ; j++)
      acc[i][j] = fzero;

  for (int k0 = 0; k0 < K; k0 += 32) {
    __syncthreads();
#pragma unroll
    for (int p = 0; p < NP; p++) {
      int c = tid + p * 256;
      if (c < BM * 4)
        gld_lds16(&A[(size_t)(bm + (c >> 2)) * K + k0 + (c & 3) * 8], &As[c * 8]);
      else {
        int cb = c - BM * 4;
        gld_lds16(&B[(size_t)(bn + (cb >> 2)) * K + k0 + (cb & 3) * 8], &Bs[cb * 8]);
      }
    }
    __syncthreads();

    bf16x8 af[MI], bfr[NJ];
#pragma unroll
    for (int i = 0; i < MI; i++)
      af[i] = *(const bf16x8*)&As[(rm + 16 * i + lm) * 32 + 8 * g];
#pragma unroll
    for (int j = 0; j < NJ; j++)
      bfr[j] = *(const bf16x8*)&Bs[(cn + 16 * j + lm) * 32 + 8 * g];
#pragma unroll
    for (int i = 0; i < MI; i++)
#pragma unroll
      for (int j = 0; j < NJ; j++)
        acc[i][j] = MFMA16(af[i], bfr[j], acc[i][j]);
  }

  if (vtg != nullptr && bn >= 2048) {
#pragma unroll
    for (int j = 0; j < NJ; j++) {
      int colv = bn + cn + 16 * j + lm - 2048;   // h*64 + dd
      int vh = colv >> 6, dd = colv & 63;
#pragma unroll
      for (int i = 0; i < MI; i++) {
        int m0 = bm + rm + 16 * i + 4 * g;
        int bb = m0 >> 11, t0 = m0 & 2047;
        __hip_bfloat16 t4[4];
#pragma unroll
        for (int r = 0; r < 4; r++) t4[r] = __float2bfloat16(acc[i][j][r]);
        *(int2*)&vtg[((size_t)(bb * 16 + vh) * 64 + dd) * 2048 + t0] =
            *(const int2*)t4;
      }
    }
    return;
  }

  // Q pre-scale: 1/sqrt(64) * log2(e)  (softmax becomes exp2)
  const float qs = (vtg != nullptr && bn < 1024) ? (0.125f * 1.4426950408889634f)
                                                 : 1.0f;
#pragma unroll
  for (int j = 0; j < NJ; j++) {
    int coln = bn + cn + 16 * j + lm;
    float bv = bias ? bias[coln] : 0.0f;
#pragma unroll
    for (int i = 0; i < MI; i++) {
#pragma unroll
      for (int r = 0; r < 4; r++) {
        int rowm = bm + rm + 16 * i + 4 * g + r;
        float v = acc[i][j][r] * qs + bv;
        if constexpr (sizeof(TC) == 2)
          C[(size_t)rowm * N + coln] = __float2bfloat16(v);
        else
          C[(size_t)rowm * N + coln] = v;
      }
    }
  }
}

// ---------------------------------------------------------------------------
// MHA, no-max softmax, S^T formulation (DS-pipe relief):
//   S^T = K·Q^T  (A=K-frag from LDS, B=Q-frag in regs; C-layout col = q = lm)
//   softmax p = exp2(s)  (log2e pre-folded into Q by gemm1)
//   P C-layout -> A-frag via in-register quad_mix (permlane swaps, no LDS)
//   O = P·V     (A=P assembled frags, B=V^T-frag from LDS)
//   l = P·1     (extra MFMA with all-ones B-frag: denominator on MFMA pipe)
// Block = (b,h) x 128 q x kv-slice; wave owns 32 q (2 mt tiles); kv-step 32.
// Latency-bound, not pipe-bound (measured r2: DS~36%, VALU~25%, MFMA~8%,
// Occupancy 30%): the cure is MORE RESIDENT BLOCKS, via split-kv z=4
// (2048 blocks = 8 blocks/CU = 32 waves/CU). Natural VGPR=56 and LDS
// 16.4KB x 8 = 131KB both fit 8 blocks/CU.
// NOTE: do NOT pin __launch_bounds__(256,8): the pin collapses the allocator
// to 32 VGPR -> full spill (measured r1: FETCH 12MB->545MB, mha 56->246us).
// ---------------------------------------------------------------------------
__global__ __launch_bounds__(256)
void mha(const __hip_bfloat16* __restrict__ qkv,
         const __hip_bfloat16* __restrict__ vtg,
         __hip_bfloat16* __restrict__ yout,
         __hip_bfloat16* __restrict__ po,
         float* __restrict__ pl,
         int nsteps)
{
  const int T = 2048, F = 3072, Cc = 1024;
  const int bh = blockIdx.x;
  const int b  = bh >> 4, h = bh & 15;
  const int qb0 = blockIdx.y * 128;
  const int z   = blockIdx.z;
  const int kvb = z * 32 * nsteps;

  const int tid  = threadIdx.x;
  const int lane = tid & 63;
  const int w    = tid >> 6;
  const int lm   = lane & 15;
  const int g    = lane >> 4;

  __shared__ __align__(16) __hip_bfloat16 Ks[2][32 * 64];   // 8 KB
  __shared__ __align__(16) __hip_bfloat16 Vs[2][64 * 32];   // 8 KB

  const size_t rowbase = (size_t)b * T * F;
  const int hoff = h * 64;
  const __hip_bfloat16* Kbase = qkv + rowbase + 1024 + hoff;
  const __hip_bfloat16* Vtb   = vtg + (size_t)(b * 16 + h) * 64 * 2048;

  const int qw = qb0 + 32 * w;
  bf16x8 aq[2][2];   // [mt][e]: Q B-frags (q rows 16mt.., d chunk 32e..)
#pragma unroll
  for (int mt = 0; mt < 2; mt++)
#pragma unroll
    for (int e = 0; e < 2; e++)
      aq[mt][e] = *(const bf16x8*)
          &qkv[rowbase + (size_t)(qw + 16 * mt + lm) * F + hoff + 32 * e + 8 * g];

  const f32x4 fzero = {0.0f, 0.0f, 0.0f, 0.0f};
  // all-ones bf16 B-frag (1.0 = 0x3f80) for the l-sum MFMA
  const short one_bf = (short)0x3f80;
  const bf16x8 vone = {one_bf, one_bf, one_bf, one_bf,
                       one_bf, one_bf, one_bf, one_bf};
  f32x4 yacc[2][4];
  f32x4 yl[2];       // yl[mt] reg r = sum_kv P for q-row 4g+r (lane-uniform in lm)
#pragma unroll
  for (int mt = 0; mt < 2; mt++) {
    yl[mt] = fzero;
#pragma unroll
    for (int c = 0; c < 4; c++) yacc[mt][c] = fzero;
  }

  // staging maps (256 chunks of 16B per tile, 1 per thread)
  const int r0  = tid >> 3;                    // K row 0..31
  const int swK = (tid & 7) ^ (r0 & 7);        // K col-chunk
  const int vdd = tid >> 2;                    // V^T row 0..63
  const int vk  = (tid & 3) ^ ((tid >> 3) & 3);// V^T col-chunk
  const int sxK = lm & 7;                      // K read swizzle
  const int sxV = (lm >> 1) & 3;               // V read swizzle

  gld_lds16(Kbase + (size_t)(kvb + r0) * F + swK * 8, &Ks[0][tid * 8]);
  gld_lds16(Vtb + (size_t)vdd * 2048 + kvb + vk * 8, &Vs[0][tid * 8]);

  for (int t = 0; t < nsteps; t++) {
    const int buf = t & 1;
    __syncthreads();   // buf DMA landed; prior reads of buf^1 done
    if (t + 1 < nsteps) {
      const int kvn = kvb + (t + 1) * 32;
      gld_lds16(Kbase + (size_t)(kvn + r0) * F + swK * 8, &Ks[buf ^ 1][tid * 8]);
      gld_lds16(Vtb + (size_t)vdd * 2048 + kvn + vk * 8, &Vs[buf ^ 1][tid * 8]);
    }

    // ---- S^T = K Q^T : 8 MFMA (A = K-frag, B = Q-frag) ----
    bf16x8 kf[2][2];
#pragma unroll
    for (int c2 = 0; c2 < 2; c2++) {
      kf[c2][0] = *(const bf16x8*)&Ks[buf][(16 * c2 + lm) * 64 + ((0 + g) ^ sxK) * 8];
      kf[c2][1] = *(const bf16x8*)&Ks[buf][(16 * c2 + lm) * 64 + ((4 + g) ^ sxK) * 8];
    }

    bf16x8 ap[2];      // P A-frags for both mt (built before the PV pass)
#pragma unroll
    for (int mt = 0; mt < 2; mt++) {
      f32x4 st[2];
      __builtin_amdgcn_s_setprio(1);
#pragma unroll
      for (int c2 = 0; c2 < 2; c2++) {
        st[c2] = MFMA16(kf[c2][0], aq[mt][0], fzero);
        st[c2] = MFMA16(kf[c2][1], aq[mt][1], st[c2]);
      }
      __builtin_amdgcn_s_setprio(0);
      // st[c2] reg r = S^T[kv = 16c2+4g+r][q = lm]

      // ---- softmax + pack (p for own q column) ----
      unsigned pkv[2][2];
#pragma unroll
      for (int c2 = 0; c2 < 2; c2++)
#pragma unroll
        for (int u = 0; u < 2; u++) {
          float p0 = __builtin_amdgcn_exp2f(st[c2][2 * u]);
          float p1 = __builtin_amdgcn_exp2f(st[c2][2 * u + 1]);
          pkv[c2][u] = pkbf(p0, p1);
        }

      // ---- C-layout -> A-frag via quad redistribution (in-register) ----
      unsigned f0 = pkv[0][0], f2 = pkv[1][0];
      quad_mix(f0, f2);
      unsigned f1 = pkv[0][1], f3 = pkv[1][1];
      quad_mix(f1, f3);
      u32x4 fv = {f0, f1, f2, f3};
      ap[mt] = __builtin_bit_cast(bf16x8, fv);
    }

    // ---- PV : shared V fragments, 4 ds_read_b128 feed both mt (8 MFMA),
    //      plus 2 l-sum MFMAs (B = ones) ----
    __builtin_amdgcn_s_setprio(1);
#pragma unroll
    for (int c = 0; c < 4; c++) {
      bf16x8 bv = *(const bf16x8*)&Vs[buf][(16 * c + lm) * 32 + (g ^ sxV) * 8];
      yacc[0][c] = MFMA16(ap[0], bv, yacc[0][c]);
      yacc[1][c] = MFMA16(ap[1], bv, yacc[1][c]);
    }
    yl[0] = MFMA16(ap[0], vone, yl[0]);
    yl[1] = MFMA16(ap[1], vone, yl[1]);
    __builtin_amdgcn_s_setprio(0);
  }

#pragma unroll
  for (int mt = 0; mt < 2; mt++) {
    if (yout != nullptr) {
      float rv[4];
#pragma unroll
      for (int r = 0; r < 4; r++)
        rv[r] = 1.0f / yl[mt][r];
#pragma unroll
      for (int c = 0; c < 4; c++)
#pragma unroll
        for (int r = 0; r < 4; r++) {
          int qrow = qw + 16 * mt + 4 * g + r;
          yout[(size_t)(b * T + qrow) * Cc + hoff + 16 * c + lm] =
              __float2bfloat16(yacc[mt][c][r] * rv[r]);
        }
    } else {
      __hip_bfloat16* pz = po + (size_t)z * 4096 * 1024;
      float* plz = pl + (size_t)z * 4096 * 16;
#pragma unroll
      for (int c = 0; c < 4; c++)
#pragma unroll
        for (int r = 0; r < 4; r++) {
          int qrow = qw + 16 * mt + 4 * g + r;
          pz[(size_t)(b * T + qrow) * Cc + hoff + 16 * c + lm] =
              __float2bfloat16(yacc[mt][c][r]);
        }
      if (lm == 0) {
#pragma unroll
        for (int r = 0; r < 4; r++)
          plz[(b * T + qw + 16 * mt + 4 * g + r) * 16 + h] = yl[mt][r];
      }
    }
  }
}

// ---------------------------------------------------------------------------
// split-kv combine: y = (sum_z O_z) / (sum_z l_z)
// ---------------------------------------------------------------------------
template<int Z>
__global__ __launch_bounds__(256)
void combine(const __hip_bfloat16* __restrict__ po,
             const float* __restrict__ pl,
             __hip_bfloat16* __restrict__ y)
{
  int idx = (blockIdx.x * 256 + threadIdx.x) * 8;   // over 4096*1024
  int row = idx >> 10, c = idx & 1023, h = c >> 6;
  float l = 0.0f;
#pragma unroll
  for (int zi = 0; zi < Z; zi++)
    l += pl[zi * 4096 * 16 + row * 16 + h];
  float rinv = 1.0f / l;
  float acc[8] = {0.f, 0.f, 0.f, 0.f, 0.f, 0.f, 0.f, 0.f};
#pragma unroll
  for (int zi = 0; zi < Z; zi++) {
    int4 raw = *(const int4*)(po + (size_t)zi * 4096 * 1024 + idx);
    const __hip_bfloat16* pa = (const __hip_bfloat16*)&raw;
#pragma unroll
    for (int j = 0; j < 8; j++) acc[j] += __bfloat162float(pa[j]);
  }
  __hip_bfloat16 t[8];
#pragma unroll
  for (int j = 0; j < 8; j++) t[j] = __float2bfloat16(acc[j] * rinv);
  *(int4*)(y + idx) = *(const int4*)t;
}

// ---------------------------------------------------------------------------
extern "C" void kernel_launch(void* const* d_in, const int* in_sizes, int n_in,
                              void* d_out, int out_size, void* d_ws, size_t ws_size,
                              hipStream_t stream)
{
  const float* x  = (const float*)d_in[0];   // [2,2048,1024]
  const float* Wa = (const float*)d_in[1];   // [3072,1024]
  const float* Wp = (const float*)d_in[2];   // [1024,1024]
  const float* bp = (const float*)d_in[3];   // [1024]
  float* out = (float*)d_out;                // [2,2048,1024] f32

  const int BT = 4096, C = 1024, F3 = 3072;
  char* ws = (char*)d_ws;
  __hip_bfloat16* qkv  = (__hip_bfloat16*)ws;                // 25.2 MB (V third unused)
  __hip_bfloat16* vtg  = (__hip_bfloat16*)(ws + 25165824);   // 8.4 MB V^T
  __hip_bfloat16* xbf  = (__hip_bfloat16*)(ws + 33554432);   // 8.4 MB
  __hip_bfloat16* yb   = xbf;  // gemm1 consumes xbf before y is written
  __hip_bfloat16* Wabf = (__hip_bfloat16*)(ws + 41943040);   // 6.3 MB
  __hip_bfloat16* Wpbf = (__hip_bfloat16*)(ws + 48234496);   // 2.1 MB
  __hip_bfloat16* Opar = (__hip_bfloat16*)(ws + 50331648);   // Z x 8.4 MB
  float*          lpar4 = (float*)(ws + 83886080);           // Z=4 layout
  float*          lpar2 = (float*)(ws + 67108864);           // Z=2 layout
  const size_t need4 = 84934656;   // 50331648 + 4*8388608 + 4*262144
  const size_t need2 = 67633152;   // 50331648 + 2*8388608 + 2*262144

  cvt_bf16<<<dim3(2048, 3), 256, 0, stream>>>(
      x, xbf, BT * C, Wa, Wabf, F3 * C, Wp, Wpbf, C * C);
  gemm_bt<128, 128, __hip_bfloat16>
      <<<dim3(F3 / 128, BT / 128), 256, 0, stream>>>(xbf, Wabf, qkv, nullptr, vtg,
                                                     BT, F3, C);
  if (ws_size >= need4) {
    // split-kv 4-way: 2048 blocks = 8 blocks/CU (natural VGPR=56 fits 8 waves/SIMD)
    mha<<<dim3(32, 16, 4), 256, 0, stream>>>(qkv, vtg, nullptr, Opar, lpar4, 16);
    combine<4><<<dim3(BT * C / 2048), 256, 0, stream>>>(Opar, lpar4, yb);
  } else if (ws_size >= need2) {
    mha<<<dim3(32, 16, 2), 256, 0, stream>>>(qkv, vtg, nullptr, Opar, lpar2, 32);
    combine<2><<<dim3(BT * C / 2048), 256, 0, stream>>>(Opar, lpar2, yb);
  } else {
    mha<<<dim3(32, 16, 1), 256, 0, stream>>>(qkv, vtg, yb, nullptr, nullptr, 64);
  }
  gemm_bt<64, 128, float>
      <<<dim3(C / 128, BT / 64), 256, 0, stream>>>(yb, Wpbf, out, bp, nullptr,
                                                   BT, C, C);
}

// Round 4
// 206.489 us; speedup vs baseline: 1.0026x; 1.0026x over previous
//
#include <hip/hip_runtime.h>
#include <hip/hip_bf16.h>
#include <stdint.h>

typedef __attribute__((ext_vector_type(8))) short bf16x8;   // 8 bf16 = 4 VGPRs
typedef __attribute__((ext_vector_type(4))) float f32x4;
typedef __attribute__((ext_vector_type(4))) unsigned u32x4;

#define MFMA16(A,B,C) __builtin_amdgcn_mfma_f32_16x16x32_bf16(A,B,C,0,0,0)

// Fragment layouts (verified m89/m91 ladder):
//  A-frag: lane l holds A[m=l&15][k=(l>>4)*8+j], j=0..7   (k-contiguous)
//  B-frag: lane l holds B^T[n=l&15][k=(l>>4)*8+j]         (k-contiguous)
//  C/D:    lane l reg r holds D[m=(l>>4)*4+r][n=l&15]

// async 16B global->LDS
__device__ inline void gld_lds16(const __hip_bfloat16* g, __hip_bfloat16* l) {
  __builtin_amdgcn_global_load_lds(
      (const __attribute__((address_space(1))) void*)g,
      (__attribute__((address_space(3))) void*)l, 16, 0, 0);
}

// pack two f32 -> one b32 holding (bf16(a) | bf16(b)<<16)
__device__ inline unsigned pkbf(float a, float b) {
  __hip_bfloat162 t = __float22bfloat162_rn(float2{a, b});
  return *(unsigned*)&t;
}

// Quad redistribution for the S^T->A-frag transform.
__device__ inline void quad_mix(unsigned &a, unsigned &b) {
#if __has_builtin(__builtin_amdgcn_permlane32_swap) && __has_builtin(__builtin_amdgcn_permlane16_swap)
  auto r1 = __builtin_amdgcn_permlane32_swap(a, b, false, false);
  auto r2 = __builtin_amdgcn_permlane16_swap(r1[0], r1[1], false, false);
  a = r2[0];
  b = r2[1];
#else
  int lane = (int)(threadIdx.x & 63);
  int g = lane >> 4;
  int lm = lane & 15;
  int slo = (((g << 1) & 3) << 4) | lm;
  int shi = ((((g << 1) | 1) & 3) << 4) | lm;
  unsigned t0 = (unsigned)__shfl((int)a, slo, 64);
  unsigned t1 = (unsigned)__shfl((int)b, slo, 64);
  unsigned t2 = (unsigned)__shfl((int)a, shi, 64);
  unsigned t3 = (unsigned)__shfl((int)b, shi, 64);
  bool hi = g >= 2;
  unsigned na = hi ? t1 : t0;
  unsigned nb = hi ? t3 : t2;
  a = na;
  b = nb;
#endif
}

// ---------------------------------------------------------------------------
// f32 -> bf16 bulk convert (one-time; x / W_attn / W_proj)
// ---------------------------------------------------------------------------
__global__ __launch_bounds__(256)
void cvt_bf16(const float* __restrict__ s0, __hip_bfloat16* __restrict__ d0, int n0,
              const float* __restrict__ s1, __hip_bfloat16* __restrict__ d1, int n1,
              const float* __restrict__ s2, __hip_bfloat16* __restrict__ d2, int n2)
{
  const float* s; __hip_bfloat16* d; int n;
  if      (blockIdx.y == 0) { s = s0; d = d0; n = n0; }
  else if (blockIdx.y == 1) { s = s1; d = d1; n = n1; }
  else                      { s = s2; d = d2; n = n2; }
  int idx = (blockIdx.x * 256 + threadIdx.x) * 8;
  if (idx >= n) return;
  float4 u0 = *(const float4*)(s + idx);
  float4 u1 = *(const float4*)(s + idx + 4);
  __hip_bfloat16 t[8];
  t[0] = __float2bfloat16(u0.x); t[1] = __float2bfloat16(u0.y);
  t[2] = __float2bfloat16(u0.z); t[3] = __float2bfloat16(u0.w);
  t[4] = __float2bfloat16(u1.x); t[5] = __float2bfloat16(u1.y);
  t[6] = __float2bfloat16(u1.z); t[7] = __float2bfloat16(u1.w);
  *(int4*)(d + idx) = *(const int4*)t;
}

// ---------------------------------------------------------------------------
// GEMM (bf16): C[m][n] = sum_k A[m*K+k]*B[n*K+k] (+bias[n])
// BMxBN tile, BK=32, global_load_lds staging, stride-32 LDS.
// (m99/m100: explicit dbuf on this structure measured neutral; left as-is.)
// ---------------------------------------------------------------------------
template<int BM, int BN, typename TC>
__global__ __launch_bounds__(256)
void gemm_bt(const __hip_bfloat16* __restrict__ A,
             const __hip_bfloat16* __restrict__ B,
             TC* __restrict__ C,
             const float* __restrict__ bias,
             __hip_bfloat16* __restrict__ vtg,
             int M, int N, int K)
{
  constexpr int MI = BM / 32;
  constexpr int NJ = BN / 32;
  constexpr int NP = (BM + BN) / 64;

  __shared__ __align__(16) __hip_bfloat16 As[BM * 32];
  __shared__ __align__(16) __hip_bfloat16 Bs[BN * 32];

  const int tid  = threadIdx.x;
  const int lane = tid & 63;
  const int w    = tid >> 6;
  const int lm   = lane & 15;
  const int g    = lane >> 4;

  const int bm = blockIdx.y * BM;
  const int bn = blockIdx.x * BN;
  const int rm = (w >> 1) * (BM / 2);
  const int cn = (w & 1) * (BN / 2);

  const f32x4 fzero = {0.0f, 0.0f, 0.0f, 0.0f};
  f32x4 acc[MI][NJ];
  for (int i = 0; i < MI; i++)
    for (int j = 0; j < NJ; j++)
      acc[i][j] = fzero;

  for (int k0 = 0; k0 < K; k0 += 32) {
    __syncthreads();
#pragma unroll
    for (int p = 0; p < NP; p++) {
      int c = tid + p * 256;
      if (c < BM * 4)
        gld_lds16(&A[(size_t)(bm + (c >> 2)) * K + k0 + (c & 3) * 8], &As[c * 8]);
      else {
        int cb = c - BM * 4;
        gld_lds16(&B[(size_t)(bn + (cb >> 2)) * K + k0 + (cb & 3) * 8], &Bs[cb * 8]);
      }
    }
    __syncthreads();

    bf16x8 af[MI], bfr[NJ];
#pragma unroll
    for (int i = 0; i < MI; i++)
      af[i] = *(const bf16x8*)&As[(rm + 16 * i + lm) * 32 + 8 * g];
#pragma unroll
    for (int j = 0; j < NJ; j++)
      bfr[j] = *(const bf16x8*)&Bs[(cn + 16 * j + lm) * 32 + 8 * g];
#pragma unroll
    for (int i = 0; i < MI; i++)
#pragma unroll
      for (int j = 0; j < NJ; j++)
        acc[i][j] = MFMA16(af[i], bfr[j], acc[i][j]);
  }

  if (vtg != nullptr && bn >= 2048) {
#pragma unroll
    for (int j = 0; j < NJ; j++) {
      int colv = bn + cn + 16 * j + lm - 2048;   // h*64 + dd
      int vh = colv >> 6, dd = colv & 63;
#pragma unroll
      for (int i = 0; i < MI; i++) {
        int m0 = bm + rm + 16 * i + 4 * g;
        int bb = m0 >> 11, t0 = m0 & 2047;
        __hip_bfloat16 t4[4];
#pragma unroll
        for (int r = 0; r < 4; r++) t4[r] = __float2bfloat16(acc[i][j][r]);
        *(int2*)&vtg[((size_t)(bb * 16 + vh) * 64 + dd) * 2048 + t0] =
            *(const int2*)t4;
      }
    }
    return;
  }

  // Q pre-scale: 1/sqrt(64) * log2(e)  (softmax becomes exp2)
  const float qs = (vtg != nullptr && bn < 1024) ? (0.125f * 1.4426950408889634f)
                                                 : 1.0f;
#pragma unroll
  for (int j = 0; j < NJ; j++) {
    int coln = bn + cn + 16 * j + lm;
    float bv = bias ? bias[coln] : 0.0f;
#pragma unroll
    for (int i = 0; i < MI; i++) {
#pragma unroll
      for (int r = 0; r < 4; r++) {
        int rowm = bm + rm + 16 * i + 4 * g + r;
        float v = acc[i][j][r] * qs + bv;
        if constexpr (sizeof(TC) == 2)
          C[(size_t)rowm * N + coln] = __float2bfloat16(v);
        else
          C[(size_t)rowm * N + coln] = v;
      }
    }
  }
}

// ---------------------------------------------------------------------------
// MHA, no-max softmax, S^T formulation.
//   S^T = K·Q^T ; p = exp2(s) ; P->A-frag via quad_mix ; O = P·V ; l = P·1.
// Block = (b,h) x 128 q x kv-slice; wave owns 32 q (2 mt tiles); kv-step 32.
//
// r3 finding: residency is hard-capped at ~4 blocks/CU (z=4 grid doubling was
// a complete null: same 56us, same 32% occupancy) -- unified VGPR+AGPR
// footprint lands in the 4-waves/SIMD granule. Occupancy lever is DEAD.
// r4 lever: kill the per-step barrier drain instead. __syncthreads() implies
// s_waitcnt vmcnt(0), draining the prefetch DMAs every step (~50% of each
// step measured as stall). Replace with T3/T4 counted-vmcnt pipeline:
//   3 LDS buffers, prefetch issued 2 steps ahead,
//   s_waitcnt vmcnt(2) (tail: 0) + raw s_barrier, sched_barrier(0) fences.
// Safety: 2 DMAs/wave/step -> oldest-2 at step t are t's loads; buffer for
// t+2 == buffer of t-1, overwritten only after barrier t (all waves done
// reading it). Do NOT reintroduce __syncthreads in this loop.
// ---------------------------------------------------------------------------
__global__ __launch_bounds__(256)
void mha(const __hip_bfloat16* __restrict__ qkv,
         const __hip_bfloat16* __restrict__ vtg,
         __hip_bfloat16* __restrict__ yout,
         __hip_bfloat16* __restrict__ po,
         float* __restrict__ pl,
         int nsteps)
{
  const int T = 2048, F = 3072, Cc = 1024;
  const int bh = blockIdx.x;
  const int b  = bh >> 4, h = bh & 15;
  const int qb0 = blockIdx.y * 128;
  const int z   = blockIdx.z;
  const int kvb = z * 32 * nsteps;

  const int tid  = threadIdx.x;
  const int lane = tid & 63;
  const int w    = tid >> 6;
  const int lm   = lane & 15;
  const int g    = lane >> 4;

  __shared__ __align__(16) __hip_bfloat16 Ks[3][32 * 64];   // 12 KB
  __shared__ __align__(16) __hip_bfloat16 Vs[3][64 * 32];   // 12 KB

  const size_t rowbase = (size_t)b * T * F;
  const int hoff = h * 64;
  const __hip_bfloat16* Kbase = qkv + rowbase + 1024 + hoff;
  const __hip_bfloat16* Vtb   = vtg + (size_t)(b * 16 + h) * 64 * 2048;

  const int qw = qb0 + 32 * w;
  bf16x8 aq[2][2];   // [mt][e]: Q B-frags (q rows 16mt.., d chunk 32e..)
#pragma unroll
  for (int mt = 0; mt < 2; mt++)
#pragma unroll
    for (int e = 0; e < 2; e++)
      aq[mt][e] = *(const bf16x8*)
          &qkv[rowbase + (size_t)(qw + 16 * mt + lm) * F + hoff + 32 * e + 8 * g];

  const f32x4 fzero = {0.0f, 0.0f, 0.0f, 0.0f};
  // all-ones bf16 B-frag (1.0 = 0x3f80) for the l-sum MFMA
  const short one_bf = (short)0x3f80;
  const bf16x8 vone = {one_bf, one_bf, one_bf, one_bf,
                       one_bf, one_bf, one_bf, one_bf};
  f32x4 yacc[2][4];
  f32x4 yl[2];       // yl[mt] reg r = sum_kv P for q-row 4g+r
#pragma unroll
  for (int mt = 0; mt < 2; mt++) {
    yl[mt] = fzero;
#pragma unroll
    for (int c = 0; c < 4; c++) yacc[mt][c] = fzero;
  }

  // staging maps (256 chunks of 16B per tile, 1 per thread)
  const int r0  = tid >> 3;                    // K row 0..31
  const int swK = (tid & 7) ^ (r0 & 7);        // K col-chunk
  const int vdd = tid >> 2;                    // V^T row 0..63
  const int vk  = (tid & 3) ^ ((tid >> 3) & 3);// V^T col-chunk
  const int sxK = lm & 7;                      // K read swizzle
  const int sxV = (lm >> 1) & 3;               // V read swizzle

  // stage step tt into LDS buffer bb (2 DMAs per thread)
  auto stage = [&](int tt, int bb) {
    const int kvn = kvb + tt * 32;
    gld_lds16(Kbase + (size_t)(kvn + r0) * F + swK * 8, &Ks[bb][tid * 8]);
    gld_lds16(Vtb + (size_t)vdd * 2048 + kvn + vk * 8, &Vs[bb][tid * 8]);
  };

  stage(0, 0);
  if (nsteps > 1) stage(1, 1);

  int bcur = 0;
  for (int t = 0; t < nsteps; t++) {
    // counted wait: oldest-2 outstanding DMAs are step-t's; keep t+1's in
    // flight across the barrier. Tail iteration drains fully.
    if (t + 1 < nsteps)
      asm volatile("s_waitcnt vmcnt(2)" ::: "memory");
    else
      asm volatile("s_waitcnt vmcnt(0)" ::: "memory");
    __builtin_amdgcn_s_barrier();
    __builtin_amdgcn_sched_barrier(0);

    if (t + 2 < nsteps) {
      int bnx = bcur + 2; if (bnx >= 3) bnx -= 3;   // == buffer of step t-1
      stage(t + 2, bnx);
    }
    __builtin_amdgcn_sched_barrier(0);

    const __hip_bfloat16* Kb = Ks[bcur];
    const __hip_bfloat16* Vb = Vs[bcur];

    // ---- S^T = K Q^T : 8 MFMA (A = K-frag, B = Q-frag) ----
    bf16x8 kf[2][2];
#pragma unroll
    for (int c2 = 0; c2 < 2; c2++) {
      kf[c2][0] = *(const bf16x8*)&Kb[(16 * c2 + lm) * 64 + ((0 + g) ^ sxK) * 8];
      kf[c2][1] = *(const bf16x8*)&Kb[(16 * c2 + lm) * 64 + ((4 + g) ^ sxK) * 8];
    }

    bf16x8 ap[2];      // P A-frags for both mt (built before the PV pass)
#pragma unroll
    for (int mt = 0; mt < 2; mt++) {
      f32x4 st[2];
      __builtin_amdgcn_s_setprio(1);
#pragma unroll
      for (int c2 = 0; c2 < 2; c2++) {
        st[c2] = MFMA16(kf[c2][0], aq[mt][0], fzero);
        st[c2] = MFMA16(kf[c2][1], aq[mt][1], st[c2]);
      }
      __builtin_amdgcn_s_setprio(0);
      // st[c2] reg r = S^T[kv = 16c2+4g+r][q = lm]

      // ---- softmax + pack (p for own q column) ----
      unsigned pkv[2][2];
#pragma unroll
      for (int c2 = 0; c2 < 2; c2++)
#pragma unroll
        for (int u = 0; u < 2; u++) {
          float p0 = __builtin_amdgcn_exp2f(st[c2][2 * u]);
          float p1 = __builtin_amdgcn_exp2f(st[c2][2 * u + 1]);
          pkv[c2][u] = pkbf(p0, p1);
        }

      // ---- C-layout -> A-frag via quad redistribution (in-register) ----
      unsigned f0 = pkv[0][0], f2 = pkv[1][0];
      quad_mix(f0, f2);
      unsigned f1 = pkv[0][1], f3 = pkv[1][1];
      quad_mix(f1, f3);
      u32x4 fv = {f0, f1, f2, f3};
      ap[mt] = __builtin_bit_cast(bf16x8, fv);
    }

    // ---- PV : shared V fragments, 4 ds_read_b128 feed both mt (8 MFMA),
    //      plus 2 l-sum MFMAs (B = ones) ----
    __builtin_amdgcn_s_setprio(1);
#pragma unroll
    for (int c = 0; c < 4; c++) {
      bf16x8 bv = *(const bf16x8*)&Vb[(16 * c + lm) * 32 + (g ^ sxV) * 8];
      yacc[0][c] = MFMA16(ap[0], bv, yacc[0][c]);
      yacc[1][c] = MFMA16(ap[1], bv, yacc[1][c]);
    }
    yl[0] = MFMA16(ap[0], vone, yl[0]);
    yl[1] = MFMA16(ap[1], vone, yl[1]);
    __builtin_amdgcn_s_setprio(0);

    bcur = bcur + 1; if (bcur >= 3) bcur = 0;
  }

#pragma unroll
  for (int mt = 0; mt < 2; mt++) {
    if (yout != nullptr) {
      float rv[4];
#pragma unroll
      for (int r = 0; r < 4; r++)
        rv[r] = 1.0f / yl[mt][r];
#pragma unroll
      for (int c = 0; c < 4; c++)
#pragma unroll
        for (int r = 0; r < 4; r++) {
          int qrow = qw + 16 * mt + 4 * g + r;
          yout[(size_t)(b * T + qrow) * Cc + hoff + 16 * c + lm] =
              __float2bfloat16(yacc[mt][c][r] * rv[r]);
        }
    } else {
      __hip_bfloat16* pz = po + (size_t)z * 4096 * 1024;
      float* plz = pl + (size_t)z * 4096 * 16;
#pragma unroll
      for (int c = 0; c < 4; c++)
#pragma unroll
        for (int r = 0; r < 4; r++) {
          int qrow = qw + 16 * mt + 4 * g + r;
          pz[(size_t)(b * T + qrow) * Cc + hoff + 16 * c + lm] =
              __float2bfloat16(yacc[mt][c][r]);
        }
      if (lm == 0) {
#pragma unroll
        for (int r = 0; r < 4; r++)
          plz[(b * T + qw + 16 * mt + 4 * g + r) * 16 + h] = yl[mt][r];
      }
    }
  }
}

// ---------------------------------------------------------------------------
// split-kv combine: y = (sum_z O_z) / (sum_z l_z)
// ---------------------------------------------------------------------------
template<int Z>
__global__ __launch_bounds__(256)
void combine(const __hip_bfloat16* __restrict__ po,
             const float* __restrict__ pl,
             __hip_bfloat16* __restrict__ y)
{
  int idx = (blockIdx.x * 256 + threadIdx.x) * 8;   // over 4096*1024
  int row = idx >> 10, c = idx & 1023, h = c >> 6;
  float l = 0.0f;
#pragma unroll
  for (int zi = 0; zi < Z; zi++)
    l += pl[zi * 4096 * 16 + row * 16 + h];
  float rinv = 1.0f / l;
  float acc[8] = {0.f, 0.f, 0.f, 0.f, 0.f, 0.f, 0.f, 0.f};
#pragma unroll
  for (int zi = 0; zi < Z; zi++) {
    int4 raw = *(const int4*)(po + (size_t)zi * 4096 * 1024 + idx);
    const __hip_bfloat16* pa = (const __hip_bfloat16*)&raw;
#pragma unroll
    for (int j = 0; j < 8; j++) acc[j] += __bfloat162float(pa[j]);
  }
  __hip_bfloat16 t[8];
#pragma unroll
  for (int j = 0; j < 8; j++) t[j] = __float2bfloat16(acc[j] * rinv);
  *(int4*)(y + idx) = *(const int4*)t;
}

// ---------------------------------------------------------------------------
extern "C" void kernel_launch(void* const* d_in, const int* in_sizes, int n_in,
                              void* d_out, int out_size, void* d_ws, size_t ws_size,
                              hipStream_t stream)
{
  const float* x  = (const float*)d_in[0];   // [2,2048,1024]
  const float* Wa = (const float*)d_in[1];   // [3072,1024]
  const float* Wp = (const float*)d_in[2];   // [1024,1024]
  const float* bp = (const float*)d_in[3];   // [1024]
  float* out = (float*)d_out;                // [2,2048,1024] f32

  const int BT = 4096, C = 1024, F3 = 3072;
  char* ws = (char*)d_ws;
  __hip_bfloat16* qkv  = (__hip_bfloat16*)ws;                // 25.2 MB (V third unused)
  __hip_bfloat16* vtg  = (__hip_bfloat16*)(ws + 25165824);   // 8.4 MB V^T
  __hip_bfloat16* xbf  = (__hip_bfloat16*)(ws + 33554432);   // 8.4 MB
  __hip_bfloat16* yb   = xbf;  // gemm1 consumes xbf before y is written
  __hip_bfloat16* Wabf = (__hip_bfloat16*)(ws + 41943040);   // 6.3 MB
  __hip_bfloat16* Wpbf = (__hip_bfloat16*)(ws + 48234496);   // 2.1 MB
  __hip_bfloat16* Opar = (__hip_bfloat16*)(ws + 50331648);   // 2 x 8.4 MB
  float*          lpar = (float*)(ws + 67108864);            // 2 x 256 KB
  const size_t need_split = 67633152;

  cvt_bf16<<<dim3(2048, 3), 256, 0, stream>>>(
      x, xbf, BT * C, Wa, Wabf, F3 * C, Wp, Wpbf, C * C);
  gemm_bt<128, 128, __hip_bfloat16>
      <<<dim3(F3 / 128, BT / 128), 256, 0, stream>>>(xbf, Wabf, qkv, nullptr, vtg,
                                                     BT, F3, C);
  if (ws_size >= need_split) {
    // split-kv 2-way: 1024 blocks = exactly the ~4 blocks/CU residency cap
    // (r3: z=4 grid doubling was null -- residency is register-capped).
    mha<<<dim3(32, 16, 2), 256, 0, stream>>>(qkv, vtg, nullptr, Opar, lpar, 32);
    combine<2><<<dim3(BT * C / 2048), 256, 0, stream>>>(Opar, lpar, yb);
  } else {
    mha<<<dim3(32, 16, 1), 256, 0, stream>>>(qkv, vtg, yb, nullptr, nullptr, 64);
  }
  gemm_bt<64, 128, float>
      <<<dim3(C / 128, BT / 64), 256, 0, stream>>>(yb, Wpbf, out, bp, nullptr,
                                                   BT, C, C);
}